// Round 4
// baseline (996.231 us; speedup 1.0000x reference)
//
#include <hip/hip_runtime.h>

constexpr int NS   = 32;
constexpr int C    = 16;
constexpr int H    = 128;
constexpr int W    = 128;
constexpr int DS   = 5;
constexpr int M    = C * DS * DS;   // 400
constexpr int NLAG = 81;            // 9x9 lags

typedef short short8 __attribute__((ext_vector_type(8)));   // 8 bf16 (4 VGPRs)
typedef float f32x4 __attribute__((ext_vector_type(4)));

// ---------------------------------------------------------------------------
// MFMA autocorr, all-(u,v) per block.
// R[((n*C+i)*C+j)*81 + u*9 + v] += sum over this block's w-chunk.
// Grid (n, wc:4, zi:2) = 256 blocks. 4 waves; per 4-row strip, wave wid
// computes row s+wid: 81 MFMAs (9u x 9v) from 12 ds_read_b128.
// LDS ring: 16 row-slots x 16 ch x 56 ushorts ([8 pre][32 data][8 post]);
// ch-stride 112B == 28 banks -> 2-way (free) b128 conflicts.
// acc: 81 f32x4 = 324 VGPRs. Output via atomicAdd (R zeroed by memset).
// ---------------------------------------------------------------------------
constexpr int CH_U   = 56;
constexpr int ROW_U  = 16 * CH_U;     // 896 ushorts = 1792 B (16B-mult)
constexpr int SMEM_B = 36864;         // max(ring 28672, reduce 9*4*256*4)

__device__ __forceinline__ unsigned short f2bf(float f) {
    unsigned int u = __float_as_uint(f);
    u += 0x7fffu + ((u >> 16) & 1u);   // RNE
    return (unsigned short)(u >> 16);
}

__device__ __forceinline__ void stage4w(const float* __restrict__ xn,
                                        unsigned short* ring, int w0, int r0, int tid) {
    // rows r0..r0+3 x 16 ch; 4 threads per (row,ch), 12 floats each, w0-8..w0+39
    const int p   = tid >> 2;
    const int sub = tid & 3;
    const int row = r0 + (p >> 4);
    const int ch  = p & 15;
    const int slot = (row + 32) & 15;
    unsigned short* dst = ring + slot * ROW_U + ch * CH_U + sub * 12;
    const float* srow = xn + ((size_t)ch * H + row) * W;
    const bool rok = (row >= 0 && row < H);
#pragma unroll
    for (int e = 0; e < 12; e += 2) {
        int w = w0 - 8 + sub * 12 + e;
        float f0 = (rok && w >= 0 && w < W) ? srow[w] : 0.f;
        float f1 = (rok && (w + 1) >= 0 && (w + 1) < W) ? srow[w + 1] : 0.f;
        ushort2 o; o.x = f2bf(f0); o.y = f2bf(f1);
        *(ushort2*)(dst + e) = o;
    }
}

__global__ __launch_bounds__(256, 1)
void autocorr_mfma(const float* __restrict__ x1, const float* __restrict__ x2,
                   float* __restrict__ R1, float* __restrict__ R2)
{
    __shared__ __align__(16) char sm[SMEM_B];
    unsigned short* ring = (unsigned short*)sm;

    const int n  = blockIdx.x;
    const int wc = blockIdx.y;
    const int zi = blockIdx.z;
    const int w0 = wc * 32;
    const int tid = threadIdx.x;
    const int lane = tid & 63;
    const int wid  = tid >> 6;
    const int q    = lane >> 4;       // k-octet
    const int mi   = lane & 15;       // i for A, j for B

    const float* xn = (zi ? x2 : x1) + (size_t)n * C * H * W;
    float* R        = (zi ? R2 : R1);

    f32x4 acc[81];
#pragma unroll
    for (int l = 0; l < 81; ++l) acc[l] = (f32x4){0.f, 0.f, 0.f, 0.f};

    stage4w(xn, ring, w0, -4, tid);
    stage4w(xn, ring, w0,  0, tid);
    stage4w(xn, ring, w0,  4, tid);
    __syncthreads();

    for (int s = 0; s < H; s += 4) {
        stage4w(xn, ring, w0, s + 8, tid);   // slots disjoint from reads below

        const int r = s + wid;               // this wave's row
        // A window: 3 aligned b128 = ushorts 8q..8q+23 of this (row, ch=mi)
        const uint4* pa = (const uint4*)(ring + (r & 15) * ROW_U + mi * CH_U + 8 * q);
        uint4 A0 = pa[0], A1 = pa[1], A2 = pa[2];
        unsigned int d[12] = {A0.x, A0.y, A0.z, A0.w, A1.x, A1.y, A1.z, A1.w,
                              A2.x, A2.y, A2.z, A2.w};
        // B frags: rows r-4..r+4, data-aligned b128
        short8 bf[9];
#pragma unroll
        for (int u = 0; u < 9; ++u) {
            const int bslot = (r + u - 4 + 16) & 15;
            bf[u] = *(const short8*)(ring + bslot * ROW_U + mi * CH_U + 8 + 8 * q);
        }
#pragma unroll
        for (int v = 0; v < 9; ++v) {
            const int off = 12 - v;          // ushort offset in window, 4..12
            const int q4  = off >> 1;
            union { unsigned int u4[4]; short8 s8; } af;
            if (off & 1) {
#pragma unroll
                for (int k2 = 0; k2 < 4; ++k2)
                    af.u4[k2] = (d[q4 + k2] >> 16) | (d[q4 + k2 + 1] << 16);
            } else {
#pragma unroll
                for (int k2 = 0; k2 < 4; ++k2) af.u4[k2] = d[q4 + k2];
            }
#pragma unroll
            for (int u = 0; u < 9; ++u)
                acc[u * 9 + v] = __builtin_amdgcn_mfma_f32_16x16x32_bf16(
                                     af.s8, bf[u], acc[u * 9 + v], 0, 0, 0);
        }
        __syncthreads();
    }

    // cross-wave reduce, one u at a time (scratch 9v*4wid*256 f32 = 36864B)
    float* sred = (float*)sm;
    for (int u = 0; u < 9; ++u) {
        __syncthreads();
#pragma unroll
        for (int v = 0; v < 9; ++v)
#pragma unroll
            for (int rg = 0; rg < 4; ++rg)
                sred[(v * 4 + wid) * 256 + (q * 4 + rg) * 16 + mi] = acc[u * 9 + v][rg];
        __syncthreads();
        // thread -> (i = tid>>4, j = tid&15)
        float* Ro = R + (((size_t)n * C + (tid >> 4)) * C + (tid & 15)) * NLAG + u * 9;
#pragma unroll
        for (int v = 0; v < 9; ++v) {
            float ssum = sred[(v * 4 + 0) * 256 + tid] + sred[(v * 4 + 1) * 256 + tid] +
                         sred[(v * 4 + 2) * 256 + tid] + sred[(v * 4 + 3) * 256 + tid];
            atomicAdd(Ro + v, ssum);
        }
    }
}

// ---------------------------------------------------------------------------
// crosscorr: P[(n*C+j)*25 + u*5 + v] = sum_{h,w} y[n,0,h,w]*x[n,j,h+u-2,w+v-2]
// float4-vectorized windows.
// ---------------------------------------------------------------------------
__global__ __launch_bounds__(256, 1)
void crosscorr_kernel(const float* __restrict__ x, const float* __restrict__ y,
                      float* __restrict__ P)
{
    const int n = blockIdx.x, j = blockIdx.y, tid = threadIdx.x;
    float acc[25];
#pragma unroll
    for (int l = 0; l < 25; ++l) acc[l] = 0.f;

    const float* yn = y + (size_t)n * H * W;
    const float* xc = x + ((size_t)n * C + j) * H * W;

    for (int g = tid; g < 32 * H; g += 256) {
        const int h = g >> 5, wg = g & 31;
        const float4 y4 = *(const float4*)(yn + h * W + wg * 4);
#pragma unroll
        for (int u = 0; u < 5; ++u) {
            const int hr = h + u - 2;
            if ((unsigned)hr >= (unsigned)H) continue;
            const float* xr = xc + hr * W + wg * 4;
            float w12[12];
            float4 t4 = (wg > 0) ? *(const float4*)(xr - 4) : make_float4(0, 0, 0, 0);
            w12[0] = t4.x; w12[1] = t4.y; w12[2] = t4.z; w12[3] = t4.w;
            t4 = *(const float4*)(xr);
            w12[4] = t4.x; w12[5] = t4.y; w12[6] = t4.z; w12[7] = t4.w;
            t4 = (wg < 31) ? *(const float4*)(xr + 4) : make_float4(0, 0, 0, 0);
            w12[8] = t4.x; w12[9] = t4.y; w12[10] = t4.z; w12[11] = t4.w;
#pragma unroll
            for (int v = 0; v < 5; ++v)
                acc[u * 5 + v] += y4.x * w12[2 + v] + y4.y * w12[3 + v] +
                                  y4.z * w12[4 + v] + y4.w * w12[5 + v];
        }
    }
    __shared__ float red[4][25];
    const int lane = tid & 63, wv = tid >> 6;
#pragma unroll
    for (int l = 0; l < 25; ++l) {
        float v = acc[l];
#pragma unroll
        for (int off = 32; off; off >>= 1) v += __shfl_down(v, off);
        if (lane == 0) red[wv][l] = v;
    }
    __syncthreads();
    if (tid < 25)
        P[((size_t)n * C + j) * 25 + tid] = red[0][tid] + red[1][tid] + red[2][tid] + red[3][tid];
}

// ---------------------------------------------------------------------------
// CG, register-resident: thread (i,jj) holds R[i,jj,0..80] in 81 VGPRs,
// matvec = 625 unrolled reg-FMAs; jj-reduce via width-16 shfl.
// (Q + aI) z = P + a*dprev,  Q[(i,a,b),(j,c,d)] = R[i,j,4+c-a,4+d-b]
// ---------------------------------------------------------------------------
__device__ __forceinline__ float block_sum512(float v, float* red, int tid)
{
#pragma unroll
    for (int off = 32; off; off >>= 1) v += __shfl_down(v, off);
    if ((tid & 63) == 0) red[tid >> 6] = v;
    __syncthreads();
    float s = red[0] + red[1] + red[2] + red[3] + red[4] + red[5] + red[6] + red[7];
    __syncthreads();
    return s;
}

__global__ __launch_bounds__(512, 1)
void cg_kernel(const float* __restrict__ R, const float* __restrict__ P,
               const float* __restrict__ dprev, const float* __restrict__ alpha,
               const float* __restrict__ reg, float* __restrict__ Dout, int iters)
{
    __shared__ float pv[16 * 28];   // p, padded stride 28
    __shared__ float ap[M];
    __shared__ float red[8];
    const int n = blockIdx.x, t = threadIdx.x;
    const float a = alpha[n] * (float)(H * W) * reg[0] / (float)(DS * DS * C);

    float Rreg[81];
    const int i = t >> 4, jj = t & 15;
    if (t < 256) {
        const float* Rp = R + (((size_t)n * C + i) * C + jj) * NLAG;
#pragma unroll
        for (int l = 0; l < 81; ++l) Rreg[l] = Rp[l];
    }

    float zreg = 0.f, rreg = 0.f, pmine = 0.f;
    if (t < M) {
        float rhs = P[(size_t)n * M + t] + a * dprev[(size_t)n * M + t];
        rreg = rhs; pmine = rhs;
        pv[(t / 25) * 28 + (t % 25)] = rhs;
    }
    __syncthreads();
    float rr = block_sum512(rreg * rreg, red, t);

    for (int it = 0; it < iters; ++it) {
        if (t < 256) {                       // waves 0..3: matvec
            float pld[25], acc[25];
            const float* pj = &pv[jj * 28];
#pragma unroll
            for (int k = 0; k < 25; ++k) pld[k] = pj[k];
#pragma unroll
            for (int k = 0; k < 25; ++k) acc[k] = 0.f;
#pragma unroll
            for (int u = 0; u < 9; ++u) {
#pragma unroll
                for (int v = 0; v < 9; ++v) {
                    const float Rv = Rreg[u * 9 + v];
#pragma unroll
                    for (int c = 0; c < 5; ++c) {
                        if (c < u - 4 || c > u) continue;
                        const int aa = 4 + c - u;
#pragma unroll
                        for (int dd = 0; dd < 5; ++dd) {
                            if (dd < v - 4 || dd > v) continue;
                            const int bb = 4 + dd - v;
                            acc[aa * 5 + bb] += Rv * pld[c * 5 + dd];
                        }
                    }
                }
            }
#pragma unroll
            for (int k = 0; k < 25; ++k) {
                float s2 = acc[k];
                s2 += __shfl_down(s2, 8, 16);
                s2 += __shfl_down(s2, 4, 16);
                s2 += __shfl_down(s2, 2, 16);
                s2 += __shfl_down(s2, 1, 16);
                acc[k] = s2;
            }
            if (jj == 0) {
#pragma unroll
                for (int k = 0; k < 25; ++k) ap[i * 25 + k] = acc[k];
            }
        }
        __syncthreads();
        float apv = 0.f;
        if (t < M) apv = ap[t] + a * pmine;
        float pAp = block_sum512((t < M) ? pmine * apv : 0.f, red, t);
        float al  = (pAp > 1e-30f) ? rr / pAp : 0.f;
        if (t < M) { zreg += al * pmine; rreg -= al * apv; }
        float rrn = block_sum512(rreg * rreg, red, t);
        float be  = (rr > 1e-30f) ? rrn / rr : 0.f;
        rr = rrn;
        if (t < M) {
            pmine = rreg + be * pmine;
            pv[(t / 25) * 28 + (t % 25)] = pmine;
        }
        __syncthreads();
    }
    if (t < M) Dout[(size_t)n * M + t] = zreg;
}

// ---------------------------------------------------------------------------
// tiny CNN (unchanged): h0 = [D2 (16ch), 1/sqrt(beta)] 5x5; 6 conv3x3,
// relu on 1..5, residual + h0[:16] after conv6
// ---------------------------------------------------------------------------
__global__ __launch_bounds__(512, 1)
void cnn_kernel(const float* __restrict__ D2, const float* __restrict__ beta,
                const float* __restrict__ w1, const float* __restrict__ b1,
                const float* __restrict__ w2, const float* __restrict__ b2,
                const float* __restrict__ w3, const float* __restrict__ b3,
                const float* __restrict__ w4, const float* __restrict__ b4,
                const float* __restrict__ w5, const float* __restrict__ b5,
                const float* __restrict__ w6, const float* __restrict__ b6,
                float* __restrict__ out)
{
    const int n = blockIdx.x, t = threadIdx.x;
    __shared__ float h0[17 * 25];
    __shared__ float bufA[16 * 25], bufB[16 * 25];
    __shared__ float wl[16 * 17 * 9];
    __shared__ float bl[16];

    if (t < 400)       h0[t] = D2[(size_t)n * M + t];
    else if (t < 425)  h0[t] = rsqrtf(beta[n]);
    __syncthreads();

    const float* ws[6] = {w1, w2, w3, w4, w5, w6};
    const float* bs[6] = {b1, b2, b3, b4, b5, b6};

    for (int l = 0; l < 6; ++l) {
        const int cin = (l == 0) ? 17 : 16;
        const int wsz = 16 * cin * 9;
        for (int idx = t; idx < wsz; idx += 512) wl[idx] = ws[l][idx];
        if (t < 16) bl[t] = bs[l][t];
        __syncthreads();

        const float* in = (l == 0) ? h0 : ((l & 1) ? bufA : bufB);
        float s = 0.f;
        if (t < 400) {
            const int o = t / 25, yy = (t % 25) / 5, xx = t % 5;
            s = bl[o];
            const float* wo = wl + o * cin * 9;
            for (int ci = 0; ci < cin; ++ci) {
                const float* ic = in + ci * 25;
#pragma unroll
                for (int ky = 0; ky < 3; ++ky) {
                    int iy = yy + ky - 1;
                    if ((unsigned)iy < 5u) {
#pragma unroll
                        for (int kx = 0; kx < 3; ++kx) {
                            int ix = xx + kx - 1;
                            if ((unsigned)ix < 5u)
                                s += wo[ci * 9 + ky * 3 + kx] * ic[iy * 5 + ix];
                        }
                    }
                }
            }
            if (l < 5) s = fmaxf(s, 0.f);
            else       s += h0[t];
        }
        __syncthreads();
        if (t < 400) {
            if (l == 5) out[(size_t)n * M + t] = s;
            else if (l & 1) bufB[t] = s;
            else            bufA[t] = s;
        }
        __syncthreads();
    }
}

// ---------------------------------------------------------------------------
extern "C" void kernel_launch(void* const* d_in, const int* in_sizes, int n_in,
                              void* d_out, int out_size, void* d_ws, size_t ws_size,
                              hipStream_t stream)
{
    (void)in_sizes; (void)n_in; (void)out_size; (void)ws_size;
    const float* x1    = (const float*)d_in[0];
    const float* x2    = (const float*)d_in[1];
    const float* d0    = (const float*)d_in[2];
    const float* y1    = (const float*)d_in[3];
    const float* y2    = (const float*)d_in[4];
    const float* alpha = (const float*)d_in[5];
    const float* beta  = (const float*)d_in[6];
    const float* reg   = (const float*)d_in[7];
    const float* w1 = (const float*)d_in[8];  const float* b1 = (const float*)d_in[9];
    const float* w2 = (const float*)d_in[10]; const float* b2 = (const float*)d_in[11];
    const float* w3 = (const float*)d_in[12]; const float* b3 = (const float*)d_in[13];
    const float* w4 = (const float*)d_in[14]; const float* b4 = (const float*)d_in[15];
    const float* w5 = (const float*)d_in[16]; const float* b5 = (const float*)d_in[17];
    const float* w6 = (const float*)d_in[18]; const float* b6 = (const float*)d_in[19];
    float* out = (float*)d_out;

    float* ws = (float*)d_ws;
    const size_t RSZ = (size_t)NS * C * C * NLAG;   // 663552
    float* R1 = ws;
    float* R2 = R1 + RSZ;
    float* P1 = R2 + RSZ;
    float* P2 = P1 + (size_t)NS * M;
    float* D1 = P2 + (size_t)NS * M;
    float* D2 = D1 + (size_t)NS * M;

    hipMemsetAsync(R1, 0, RSZ * sizeof(float), stream);
    hipMemsetAsync(R2, 0, RSZ * sizeof(float), stream);

    autocorr_mfma<<<dim3(NS, 4, 2), 256, 0, stream>>>(x1, x2, R1, R2);
    crosscorr_kernel<<<dim3(NS, C), 256, 0, stream>>>(x1, y1, P1);
    crosscorr_kernel<<<dim3(NS, C), 256, 0, stream>>>(x2, y2, P2);
    cg_kernel<<<NS, 512, 0, stream>>>(R1, P1, d0, alpha, reg, D1, 3);
    cg_kernel<<<NS, 512, 0, stream>>>(R2, P2, D1, alpha, reg, D2, 7);
    cnn_kernel<<<NS, 512, 0, stream>>>(D2, beta, w1, b1, w2, b2, w3, b3,
                                       w4, b4, w5, b5, w6, b6, out);
}

// Round 5
// 436.996 us; speedup vs baseline: 2.2797x; 2.2797x over previous
//
#include <hip/hip_runtime.h>
#include <hip/hip_bf16.h>

constexpr int NS   = 32;
constexpr int C    = 16;
constexpr int H    = 128;
constexpr int W    = 128;
constexpr int DS   = 5;
constexpr int M    = C * DS * DS;   // 400
constexpr int NLAG = 81;            // 9x9 lags

typedef short short8 __attribute__((ext_vector_type(8)));   // 8 bf16 (4 VGPRs)
typedef float f32x4 __attribute__((ext_vector_type(4)));

// ---------------------------------------------------------------------------
// MFMA autocorr, (u,v)-pair-split across blocks (u-major p = u*9+v).
// Grid (n:32, zi:2, ug:4); subsets [0,20) [20,40) [40,60) [60,81) -> each block
// holds 20-21 f32x4 accumulators (~84 VGPR, no spill) and needs only 3 B-frags.
// Block covers full W (4 chunk-MFMAs per row) -> exclusive R stores, no atomics.
// LDS ring: 16 row-slots x 16 ch x 152 ushorts ([8 zero][128 data][8 zero][8 pad]);
// ch-stride 304 B -> 2-way (free) b128 bank pattern. 76 KiB.
// ---------------------------------------------------------------------------
constexpr int CH_U   = 152;
constexpr int ROW_U  = 16 * CH_U;          // 2432 ushorts
constexpr int RING_B = 16 * ROW_U * 2;     // 77824 B

__device__ __forceinline__ unsigned int pk_bf16(float a, float b) {
    union { __hip_bfloat162 h; unsigned int u; } cv;
    cv.h = __float22bfloat162_rn(make_float2(a, b));
    return cv.u;
}

__device__ __forceinline__ void stage_full(const float* __restrict__ xn,
                                           unsigned short* ring, int r0, int tid) {
    // 4 rows x 16 ch x 19 b128-groups = 1216 items
    for (int it = tid; it < 4 * 16 * 19; it += 256) {
        const int rr  = it / (16 * 19);
        const int rem = it - rr * (16 * 19);
        const int ch  = rem / 19;
        const int g   = rem - ch * 19;
        const int row = r0 + rr;
        const int slot = (row + 32) & 15;
        unsigned short* dst = ring + slot * ROW_U + ch * CH_U + 8 * g;
        uint4 o = make_uint4(0u, 0u, 0u, 0u);
        if (g >= 1 && g <= 16 && row >= 0 && row < H) {
            const float4* s4 = (const float4*)(xn + ((size_t)ch * H + row) * W + 8 * (g - 1));
            float4 va = s4[0], vb = s4[1];
            o.x = pk_bf16(va.x, va.y); o.y = pk_bf16(va.z, va.w);
            o.z = pk_bf16(vb.x, vb.y); o.w = pk_bf16(vb.z, vb.w);
        }
        *(uint4*)dst = o;
    }
}

template<int P0, int P1>
__device__ __forceinline__ void autocorr_body(const float* __restrict__ xn,
                                              float* __restrict__ Rn,
                                              char* sm, int tid)
{
    constexpr int U0 = P0 / 9;
    constexpr int U1 = (P1 - 1) / 9;
    constexpr int NB = U1 - U0 + 1;        // 3
    constexpr int NP = P1 - P0;            // 20 or 21

    unsigned short* ring = (unsigned short*)sm;
    const int lane = tid & 63;
    const int wid  = tid >> 6;             // wave -> row mod 4
    const int q    = lane >> 4;            // k-octet
    const int mi   = lane & 15;            // channel (i for A, j for B)

    f32x4 acc[NP];
#pragma unroll
    for (int l = 0; l < NP; ++l) acc[l] = (f32x4){0.f, 0.f, 0.f, 0.f};

    stage_full(xn, ring, -4, tid);
    stage_full(xn, ring,  0, tid);
    stage_full(xn, ring,  4, tid);
    __syncthreads();

    for (int s = 0; s < H; s += 4) {
        stage_full(xn, ring, s + 8, tid);   // slots (s+8..s+11)&15 disjoint from reads

        const int r = s + wid;
        const unsigned short* rowA = ring + (r & 15) * ROW_U + mi * CH_U;
#pragma unroll
        for (int c = 0; c < 4; ++c) {
            const int w0 = 32 * c;
            // A window: ushorts w0+8q .. w0+8q+23  (w = w0+8q-8 .. w0+8q+15)
            const uint4* pa = (const uint4*)(rowA + w0 + 8 * q);
            uint4 A0 = pa[0], A1 = pa[1], A2 = pa[2];
            unsigned int d[12] = {A0.x, A0.y, A0.z, A0.w, A1.x, A1.y, A1.z, A1.w,
                                  A2.x, A2.y, A2.z, A2.w};
            // B frags for this subset's u values (data-aligned b128)
            short8 bf[NB];
#pragma unroll
            for (int u = U0; u <= U1; ++u)
                bf[u - U0] = *(const short8*)(ring + ((r + u - 4 + 16) & 15) * ROW_U +
                                              mi * CH_U + 8 + w0 + 8 * q);
#pragma unroll
            for (int v = 0; v < 9; ++v) {
                const int off = 12 - v;     // ushort offset: A[k] = x_i[w0+k+4-v]
                const int q4  = off >> 1;
                union { unsigned int u4[4]; short8 s8; } af;
                if (off & 1) {
#pragma unroll
                    for (int k2 = 0; k2 < 4; ++k2)
                        af.u4[k2] = (d[q4 + k2] >> 16) | (d[q4 + k2 + 1] << 16);
                } else {
#pragma unroll
                    for (int k2 = 0; k2 < 4; ++k2) af.u4[k2] = d[q4 + k2];
                }
#pragma unroll
                for (int u = U0; u <= U1; ++u) {
                    if (u * 9 + v >= P0 && u * 9 + v < P1)   // compile-time folded
                        acc[u * 9 + v - P0] = __builtin_amdgcn_mfma_f32_16x16x32_bf16(
                            af.s8, bf[u - U0], acc[u * 9 + v - P0], 0, 0, 0);
                }
            }
        }
        __syncthreads();
    }

    // cross-wave reduce in <=9-pair chunks (scratch 9*4*256*4 = 36864 B in ring)
    float* sred = (float*)sm;
#pragma unroll
    for (int cb = 0; cb < NP; cb += 9) {
        constexpr int REM = 0;  (void)REM;
        const int nc = (NP - cb < 9) ? (NP - cb) : 9;
        __syncthreads();
#pragma unroll
        for (int pp = 0; pp < 9; ++pp) {
            if (pp < nc) {
#pragma unroll
                for (int rg = 0; rg < 4; ++rg)
                    sred[(pp * 4 + wid) * 256 + (q * 4 + rg) * 16 + mi] = acc[cb + pp][rg];
            }
        }
        __syncthreads();
        // thread t -> (i = t>>4, j = t&15): flat (i*C+j) == t
#pragma unroll
        for (int pp = 0; pp < 9; ++pp) {
            if (pp < nc) {
                float ssum = sred[(pp * 4 + 0) * 256 + tid] + sred[(pp * 4 + 1) * 256 + tid] +
                             sred[(pp * 4 + 2) * 256 + tid] + sred[(pp * 4 + 3) * 256 + tid];
                Rn[(size_t)tid * NLAG + P0 + cb + pp] = ssum;
            }
        }
    }
}

__global__ __launch_bounds__(256, 1)
void autocorr_mfma(const float* __restrict__ x1, const float* __restrict__ x2,
                   float* __restrict__ R1, float* __restrict__ R2)
{
    __shared__ __align__(16) char sm[RING_B];
    const int n  = blockIdx.x;
    const int zi = blockIdx.y;
    const int ug = blockIdx.z;
    const int tid = threadIdx.x;

    const float* xn = (zi ? x2 : x1) + (size_t)n * C * H * W;
    float* Rn       = (zi ? R2 : R1) + (size_t)n * C * C * NLAG;

    switch (ug) {
        case 0: autocorr_body< 0, 20>(xn, Rn, sm, tid); break;
        case 1: autocorr_body<20, 40>(xn, Rn, sm, tid); break;
        case 2: autocorr_body<40, 60>(xn, Rn, sm, tid); break;
        default: autocorr_body<60, 81>(xn, Rn, sm, tid); break;
    }
}

// ---------------------------------------------------------------------------
// crosscorr (both inputs in one launch, z = input):
// P[(n*C+j)*25 + u*5 + v] = sum_{h,w} y[n,0,h,w]*x[n,j,h+u-2,w+v-2]
// ---------------------------------------------------------------------------
__global__ __launch_bounds__(256, 1)
void crosscorr_kernel(const float* __restrict__ x1, const float* __restrict__ y1,
                      const float* __restrict__ x2, const float* __restrict__ y2,
                      float* __restrict__ P1, float* __restrict__ P2)
{
    const int n = blockIdx.x, j = blockIdx.y, zi = blockIdx.z, tid = threadIdx.x;
    const float* x = zi ? x2 : x1;
    const float* y = zi ? y2 : y1;
    float* P       = zi ? P2 : P1;

    float acc[25];
#pragma unroll
    for (int l = 0; l < 25; ++l) acc[l] = 0.f;

    const float* yn = y + (size_t)n * H * W;
    const float* xc = x + ((size_t)n * C + j) * H * W;

    for (int g = tid; g < 32 * H; g += 256) {
        const int h = g >> 5, wg = g & 31;
        const float4 y4 = *(const float4*)(yn + h * W + wg * 4);
#pragma unroll
        for (int u = 0; u < 5; ++u) {
            const int hr = h + u - 2;
            if ((unsigned)hr >= (unsigned)H) continue;
            const float* xr = xc + hr * W + wg * 4;
            float w12[12];
            float4 t4 = (wg > 0) ? *(const float4*)(xr - 4) : make_float4(0, 0, 0, 0);
            w12[0] = t4.x; w12[1] = t4.y; w12[2] = t4.z; w12[3] = t4.w;
            t4 = *(const float4*)(xr);
            w12[4] = t4.x; w12[5] = t4.y; w12[6] = t4.z; w12[7] = t4.w;
            t4 = (wg < 31) ? *(const float4*)(xr + 4) : make_float4(0, 0, 0, 0);
            w12[8] = t4.x; w12[9] = t4.y; w12[10] = t4.z; w12[11] = t4.w;
#pragma unroll
            for (int v = 0; v < 5; ++v)
                acc[u * 5 + v] += y4.x * w12[2 + v] + y4.y * w12[3 + v] +
                                  y4.z * w12[4 + v] + y4.w * w12[5 + v];
        }
    }
    __shared__ float red[4][25];
    const int lane = tid & 63, wv = tid >> 6;
#pragma unroll
    for (int l = 0; l < 25; ++l) {
        float v = acc[l];
#pragma unroll
        for (int off = 32; off; off >>= 1) v += __shfl_down(v, off);
        if (lane == 0) red[wv][l] = v;
    }
    __syncthreads();
    if (tid < 25)
        P[((size_t)n * C + j) * 25 + tid] = red[0][tid] + red[1][tid] + red[2][tid] + red[3][tid];
}

// ---------------------------------------------------------------------------
// CG, register-resident R: thread (i,jj) holds R[i,jj,0..80] in 81 VGPRs,
// matvec = 625 unrolled reg-FMAs; jj-reduce via width-16 shfl.
// (Q + aI) z = P + a*dprev,  Q[(i,a,b),(j,c,d)] = R[i,j,4+c-a,4+d-b]
// ---------------------------------------------------------------------------
__device__ __forceinline__ float block_sum512(float v, float* red, int tid)
{
#pragma unroll
    for (int off = 32; off; off >>= 1) v += __shfl_down(v, off);
    if ((tid & 63) == 0) red[tid >> 6] = v;
    __syncthreads();
    float s = red[0] + red[1] + red[2] + red[3] + red[4] + red[5] + red[6] + red[7];
    __syncthreads();
    return s;
}

__global__ __launch_bounds__(512, 1)
void cg_kernel(const float* __restrict__ R, const float* __restrict__ P,
               const float* __restrict__ dprev, const float* __restrict__ alpha,
               const float* __restrict__ reg, float* __restrict__ Dout, int iters)
{
    __shared__ float pv[16 * 28];
    __shared__ float ap[M];
    __shared__ float red[8];
    const int n = blockIdx.x, t = threadIdx.x;
    const float a = alpha[n] * (float)(H * W) * reg[0] / (float)(DS * DS * C);

    float Rreg[81];
    const int i = t >> 4, jj = t & 15;
    if (t < 256) {
        const float* Rp = R + (((size_t)n * C + i) * C + jj) * NLAG;
#pragma unroll
        for (int l = 0; l < 81; ++l) Rreg[l] = Rp[l];
    }

    float zreg = 0.f, rreg = 0.f, pmine = 0.f;
    if (t < M) {
        float rhs = P[(size_t)n * M + t] + a * dprev[(size_t)n * M + t];
        rreg = rhs; pmine = rhs;
        pv[(t / 25) * 28 + (t % 25)] = rhs;
    }
    __syncthreads();
    float rr = block_sum512(rreg * rreg, red, t);

    for (int it = 0; it < iters; ++it) {
        if (t < 256) {
            float pld[25], acc[25];
            const float* pj = &pv[jj * 28];
#pragma unroll
            for (int k = 0; k < 25; ++k) pld[k] = pj[k];
#pragma unroll
            for (int k = 0; k < 25; ++k) acc[k] = 0.f;
#pragma unroll
            for (int u = 0; u < 9; ++u) {
#pragma unroll
                for (int v = 0; v < 9; ++v) {
                    const float Rv = Rreg[u * 9 + v];
#pragma unroll
                    for (int c = 0; c < 5; ++c) {
                        if (c < u - 4 || c > u) continue;
                        const int aa = 4 + c - u;
#pragma unroll
                        for (int dd = 0; dd < 5; ++dd) {
                            if (dd < v - 4 || dd > v) continue;
                            const int bb = 4 + dd - v;
                            acc[aa * 5 + bb] += Rv * pld[c * 5 + dd];
                        }
                    }
                }
            }
#pragma unroll
            for (int k = 0; k < 25; ++k) {
                float s2 = acc[k];
                s2 += __shfl_down(s2, 8, 16);
                s2 += __shfl_down(s2, 4, 16);
                s2 += __shfl_down(s2, 2, 16);
                s2 += __shfl_down(s2, 1, 16);
                acc[k] = s2;
            }
            if (jj == 0) {
#pragma unroll
                for (int k = 0; k < 25; ++k) ap[i * 25 + k] = acc[k];
            }
        }
        __syncthreads();
        float apv = 0.f;
        if (t < M) apv = ap[t] + a * pmine;
        float pAp = block_sum512((t < M) ? pmine * apv : 0.f, red, t);
        float al  = (pAp > 1e-30f) ? rr / pAp : 0.f;
        if (t < M) { zreg += al * pmine; rreg -= al * apv; }
        float rrn = block_sum512(rreg * rreg, red, t);
        float be  = (rr > 1e-30f) ? rrn / rr : 0.f;
        rr = rrn;
        if (t < M) {
            pmine = rreg + be * pmine;
            pv[(t / 25) * 28 + (t % 25)] = pmine;
        }
        __syncthreads();
    }
    if (t < M) Dout[(size_t)n * M + t] = zreg;
}

// ---------------------------------------------------------------------------
// tiny CNN: h0 = [D2 (16ch), 1/sqrt(beta)] 5x5; 6 conv3x3, relu 1..5,
// residual + h0[:16] after conv6
// ---------------------------------------------------------------------------
__global__ __launch_bounds__(512, 1)
void cnn_kernel(const float* __restrict__ D2, const float* __restrict__ beta,
                const float* __restrict__ w1, const float* __restrict__ b1,
                const float* __restrict__ w2, const float* __restrict__ b2,
                const float* __restrict__ w3, const float* __restrict__ b3,
                const float* __restrict__ w4, const float* __restrict__ b4,
                const float* __restrict__ w5, const float* __restrict__ b5,
                const float* __restrict__ w6, const float* __restrict__ b6,
                float* __restrict__ out)
{
    const int n = blockIdx.x, t = threadIdx.x;
    __shared__ float h0[17 * 25];
    __shared__ float bufA[16 * 25], bufB[16 * 25];
    __shared__ float wl[16 * 17 * 9];
    __shared__ float bl[16];

    if (t < 400)       h0[t] = D2[(size_t)n * M + t];
    else if (t < 425)  h0[t] = rsqrtf(beta[n]);
    __syncthreads();

    const float* ws[6] = {w1, w2, w3, w4, w5, w6};
    const float* bs[6] = {b1, b2, b3, b4, b5, b6};

    for (int l = 0; l < 6; ++l) {
        const int cin = (l == 0) ? 17 : 16;
        const int wsz = 16 * cin * 9;
        for (int idx = t; idx < wsz; idx += 512) wl[idx] = ws[l][idx];
        if (t < 16) bl[t] = bs[l][t];
        __syncthreads();

        const float* in = (l == 0) ? h0 : ((l & 1) ? bufA : bufB);
        float s = 0.f;
        if (t < 400) {
            const int o = t / 25, yy = (t % 25) / 5, xx = t % 5;
            s = bl[o];
            const float* wo = wl + o * cin * 9;
            for (int ci = 0; ci < cin; ++ci) {
                const float* ic = in + ci * 25;
#pragma unroll
                for (int ky = 0; ky < 3; ++ky) {
                    int iy = yy + ky - 1;
                    if ((unsigned)iy < 5u) {
#pragma unroll
                        for (int kx = 0; kx < 3; ++kx) {
                            int ix = xx + kx - 1;
                            if ((unsigned)ix < 5u)
                                s += wo[ci * 9 + ky * 3 + kx] * ic[iy * 5 + ix];
                        }
                    }
                }
            }
            if (l < 5) s = fmaxf(s, 0.f);
            else       s += h0[t];
        }
        __syncthreads();
        if (t < 400) {
            if (l == 5) out[(size_t)n * M + t] = s;
            else if (l & 1) bufB[t] = s;
            else            bufA[t] = s;
        }
        __syncthreads();
    }
}

// ---------------------------------------------------------------------------
extern "C" void kernel_launch(void* const* d_in, const int* in_sizes, int n_in,
                              void* d_out, int out_size, void* d_ws, size_t ws_size,
                              hipStream_t stream)
{
    (void)in_sizes; (void)n_in; (void)out_size; (void)ws_size;
    const float* x1    = (const float*)d_in[0];
    const float* x2    = (const float*)d_in[1];
    const float* d0    = (const float*)d_in[2];
    const float* y1    = (const float*)d_in[3];
    const float* y2    = (const float*)d_in[4];
    const float* alpha = (const float*)d_in[5];
    const float* beta  = (const float*)d_in[6];
    const float* reg   = (const float*)d_in[7];
    const float* w1 = (const float*)d_in[8];  const float* b1 = (const float*)d_in[9];
    const float* w2 = (const float*)d_in[10]; const float* b2 = (const float*)d_in[11];
    const float* w3 = (const float*)d_in[12]; const float* b3 = (const float*)d_in[13];
    const float* w4 = (const float*)d_in[14]; const float* b4 = (const float*)d_in[15];
    const float* w5 = (const float*)d_in[16]; const float* b5 = (const float*)d_in[17];
    const float* w6 = (const float*)d_in[18]; const float* b6 = (const float*)d_in[19];
    float* out = (float*)d_out;

    float* ws = (float*)d_ws;
    const size_t RSZ = (size_t)NS * C * C * NLAG;   // 663552
    float* R1 = ws;
    float* R2 = R1 + RSZ;
    float* P1 = R2 + RSZ;
    float* P2 = P1 + (size_t)NS * M;
    float* D1 = P2 + (size_t)NS * M;
    float* D2 = D1 + (size_t)NS * M;

    autocorr_mfma<<<dim3(NS, 2, 4), 256, 0, stream>>>(x1, x2, R1, R2);
    crosscorr_kernel<<<dim3(NS, C, 2), 256, 0, stream>>>(x1, y1, x2, y2, P1, P2);
    cg_kernel<<<NS, 512, 0, stream>>>(R1, P1, d0, alpha, reg, D1, 3);
    cg_kernel<<<NS, 512, 0, stream>>>(R2, P2, D1, alpha, reg, D2, 7);
    cnn_kernel<<<NS, 512, 0, stream>>>(D2, beta, w1, b1, w2, b2, w3, b3,
                                       w4, b4, w5, b5, w6, b6, out);
}

// Round 6
// 368.678 us; speedup vs baseline: 2.7022x; 1.1853x over previous
//
#include <hip/hip_runtime.h>
#include <hip/hip_bf16.h>

constexpr int NS   = 32;
constexpr int C    = 16;
constexpr int H    = 128;
constexpr int W    = 128;
constexpr int DS   = 5;
constexpr int M    = C * DS * DS;   // 400
constexpr int NLAG = 81;

typedef short short8 __attribute__((ext_vector_type(8)));
typedef float f32x4 __attribute__((ext_vector_type(4)));

// bf16 staging layout: xb[zi][n][row][ch][160] ushort:
//   [8 zero][128 data][8 zero][16 zero pad]  -> row-chunk = 16ch*160*2 = 5120 B
constexpr int CH_U    = 160;
constexpr int SLOT_U  = 16 * CH_U;            // 2560 us = 5120 B per row-slot
constexpr int SLOT_B  = SLOT_U * 2;
constexpr int RING_B  = 16 * SLOT_B;          // 81920 B
constexpr size_t XB_US_PER_IN = (size_t)NS * H * 16 * CH_U;   // 10,485,760

__device__ __forceinline__ unsigned int pk_bf16(float a, float b) {
    union { __hip_bfloat162 h; unsigned int u; } cv;
    cv.h = __float22bfloat162_rn(make_float2(a, b));
    return cv.u;
}

__device__ __forceinline__ void gl_lds16(const void* g, void* l) {
    __builtin_amdgcn_global_load_lds(
        (const __attribute__((address_space(1))) unsigned int*)g,
        (__attribute__((address_space(3))) unsigned int*)l, 16, 0, 0);
}

// ---------------------------------------------------------------------------
// prep kernel: blocks 0..1023 convert x->xb (bf16 halo layout);
// blocks 1024..2047 compute crosscorr P.
// ---------------------------------------------------------------------------
__global__ __launch_bounds__(256, 1)
void prep_kernel(const float* __restrict__ x1, const float* __restrict__ x2,
                 const float* __restrict__ y1, const float* __restrict__ y2,
                 unsigned short* __restrict__ xb,
                 float* __restrict__ P1, float* __restrict__ P2)
{
    const int b = blockIdx.x, tid = threadIdx.x;
    if (b < 1024) {
        // cvt: (n, zi, rowgroup of 8)
        const int n = b & 31, zi = (b >> 5) & 1, rg = b >> 6;
        const float* xn = (zi ? x2 : x1) + (size_t)n * C * H * W;
        uint4* dst = (uint4*)(xb + (size_t)zi * XB_US_PER_IN +
                              ((size_t)n * H) * SLOT_U);
        for (int f = tid; f < 8 * 16 * 20; f += 256) {
            const int rc = f / 20, g = f - rc * 20;
            const int row = rg * 8 + (rc >> 4), ch = rc & 15;
            uint4 o = make_uint4(0u, 0u, 0u, 0u);
            if (g >= 1 && g <= 16) {
                const float4* s4 = (const float4*)(xn + ((size_t)ch * H + row) * W + (g - 1) * 8);
                float4 va = s4[0], vb = s4[1];
                o.x = pk_bf16(va.x, va.y); o.y = pk_bf16(va.z, va.w);
                o.z = pk_bf16(vb.x, vb.y); o.w = pk_bf16(vb.z, vb.w);
            }
            dst[((size_t)row * 16 + ch) * 20 + g] = o;
        }
        return;
    }
    // crosscorr
    const int b2 = b - 1024;
    const int n = b2 & 31, j = (b2 >> 5) & 15, zi = b2 >> 9;
    const float* x = zi ? x2 : x1;
    const float* y = zi ? y2 : y1;
    float* P       = zi ? P2 : P1;

    float acc[25];
#pragma unroll
    for (int l = 0; l < 25; ++l) acc[l] = 0.f;
    const float* yn = y + (size_t)n * H * W;
    const float* xc = x + ((size_t)n * C + j) * H * W;

    for (int g = tid; g < 32 * H; g += 256) {
        const int h = g >> 5, wg = g & 31;
        const float4 y4 = *(const float4*)(yn + h * W + wg * 4);
#pragma unroll
        for (int u = 0; u < 5; ++u) {
            const int hr = h + u - 2;
            if ((unsigned)hr >= (unsigned)H) continue;
            const float* xr = xc + hr * W + wg * 4;
            float w12[12];
            float4 t4 = (wg > 0) ? *(const float4*)(xr - 4) : make_float4(0, 0, 0, 0);
            w12[0] = t4.x; w12[1] = t4.y; w12[2] = t4.z; w12[3] = t4.w;
            t4 = *(const float4*)(xr);
            w12[4] = t4.x; w12[5] = t4.y; w12[6] = t4.z; w12[7] = t4.w;
            t4 = (wg < 31) ? *(const float4*)(xr + 4) : make_float4(0, 0, 0, 0);
            w12[8] = t4.x; w12[9] = t4.y; w12[10] = t4.z; w12[11] = t4.w;
#pragma unroll
            for (int v = 0; v < 5; ++v)
                acc[u * 5 + v] += y4.x * w12[2 + v] + y4.y * w12[3 + v] +
                                  y4.z * w12[4 + v] + y4.w * w12[5 + v];
        }
    }
    __shared__ float red[4][25];
    const int lane = tid & 63, wv = tid >> 6;
#pragma unroll
    for (int l = 0; l < 25; ++l) {
        float v = acc[l];
#pragma unroll
        for (int off = 32; off; off >>= 1) v += __shfl_down(v, off);
        if (lane == 0) red[wv][l] = v;
    }
    __syncthreads();
    if (tid < 25)
        P[((size_t)n * C + j) * 25 + tid] = red[0][tid] + red[1][tid] + red[2][tid] + red[3][tid];
}

// ---------------------------------------------------------------------------
// MFMA autocorr: grid (n, zi, ug:4), 512 threads (8 waves).
// Wave wid: row = s + (wid&3), chunk-half = wid>>2 (chunks 2h, 2h+1).
// Staging: async global_load_lds dwordx4 from pre-converted xb (5 KB/row).
// ---------------------------------------------------------------------------
template<int P0, int P1>
__device__ __forceinline__ void autocorr_body(const unsigned short* __restrict__ xn,
                                              float* __restrict__ Rn,
                                              char* sm, int tid)
{
    constexpr int U0 = P0 / 9;
    constexpr int U1 = (P1 - 1) / 9;
    constexpr int NB = U1 - U0 + 1;     // 3
    constexpr int NP = P1 - P0;         // 20 or 21

    unsigned short* ring = (unsigned short*)sm;
    const int lane = tid & 63;
    const int wid  = tid >> 6;          // 0..7
    const int q    = lane >> 4;
    const int mi   = lane & 15;
    const int rh   = wid & 3;           // row within strip
    const int chh  = wid >> 2;          // chunk half

    f32x4 acc[NP];
#pragma unroll
    for (int l = 0; l < NP; ++l) acc[l] = (f32x4){0.f, 0.f, 0.f, 0.f};

    const char* gb = (const char*)xn;

    // init: zero slots 12..15 (rows -4..-1); async-load rows 0..7 -> slots 0..7
    for (int f = tid; f < 4 * 320; f += 512)
        ((uint4*)sm)[(12 + (f >> 8) * 0 + f / 320) * 320 + (f % 320)] = make_uint4(0, 0, 0, 0);
    for (int f = wid; f < 40; f += 8) {
        const int row = f / 5, e = f - row * 5;
        gl_lds16(gb + (size_t)row * SLOT_B + e * 1024 + lane * 16,
                 sm + row * SLOT_B + e * 1024);
    }
    __syncthreads();

    for (int s = 0; s < H; s += 4) {
        // stage rows s+8..s+11
        if (s < H - 8) {
            for (int f = wid; f < 20; f += 8) {
                const int row = s + 8 + f / 5, e = f - (f / 5) * 5;
                gl_lds16(gb + (size_t)row * SLOT_B + e * 1024 + lane * 16,
                         sm + (row & 15) * SLOT_B + e * 1024);
            }
        } else {
            for (int f = tid; f < 4 * 320; f += 512)
                ((uint4*)sm)[(((s + 8 + f / 320) & 15)) * 320 + (f % 320)] = make_uint4(0, 0, 0, 0);
        }

        const int r = s + rh;
        const unsigned short* rowA = ring + (r & 15) * SLOT_U + mi * CH_U;
#pragma unroll
        for (int cc = 0; cc < 2; ++cc) {
            const int w0 = (chh * 2 + cc) * 32;
            const uint4* pa = (const uint4*)(rowA + w0 + 8 * q);
            uint4 A0 = pa[0], A1 = pa[1], A2 = pa[2];
            unsigned int d[12] = {A0.x, A0.y, A0.z, A0.w, A1.x, A1.y, A1.z, A1.w,
                                  A2.x, A2.y, A2.z, A2.w};
            short8 bf[NB];
#pragma unroll
            for (int u = U0; u <= U1; ++u)
                bf[u - U0] = *(const short8*)(ring + ((r + u - 4 + 16) & 15) * SLOT_U +
                                              mi * CH_U + 8 + w0 + 8 * q);
#pragma unroll
            for (int v = 0; v < 9; ++v) {
                const int off = 12 - v;
                const int q4  = off >> 1;
                union { unsigned int u4[4]; short8 s8; } af;
                if (off & 1) {
#pragma unroll
                    for (int k2 = 0; k2 < 4; ++k2)
                        af.u4[k2] = (d[q4 + k2] >> 16) | (d[q4 + k2 + 1] << 16);
                } else {
#pragma unroll
                    for (int k2 = 0; k2 < 4; ++k2) af.u4[k2] = d[q4 + k2];
                }
#pragma unroll
                for (int u = U0; u <= U1; ++u) {
                    if (u * 9 + v >= P0 && u * 9 + v < P1)
                        acc[u * 9 + v - P0] = __builtin_amdgcn_mfma_f32_16x16x32_bf16(
                            af.s8, bf[u - U0], acc[u * 9 + v - P0], 0, 0, 0);
                }
            }
        }
        __syncthreads();
    }

    // cross-wave reduce over 8 partials, 9 pairs at a time
    float* sred = (float*)sm;
#pragma unroll
    for (int cb = 0; cb < NP; cb += 9) {
        const int nc = (NP - cb < 9) ? (NP - cb) : 9;
        __syncthreads();
#pragma unroll
        for (int pp = 0; pp < 9; ++pp) {
            if (pp < nc) {
#pragma unroll
                for (int rg = 0; rg < 4; ++rg)
                    sred[(pp * 8 + wid) * 256 + (q * 4 + rg) * 16 + mi] = acc[cb + pp][rg];
            }
        }
        __syncthreads();
        if (tid < 256) {
#pragma unroll
            for (int pp = 0; pp < 9; ++pp) {
                if (pp < nc) {
                    float ssum = 0.f;
#pragma unroll
                    for (int w8 = 0; w8 < 8; ++w8)
                        ssum += sred[(pp * 8 + w8) * 256 + tid];
                    Rn[(size_t)tid * NLAG + P0 + cb + pp] = ssum;
                }
            }
        }
    }
}

__global__ __launch_bounds__(512, 2)
void autocorr_mfma(const unsigned short* __restrict__ xb,
                   float* __restrict__ R1, float* __restrict__ R2)
{
    __shared__ __align__(16) char sm[RING_B];
    const int n = blockIdx.x, zi = blockIdx.y, ug = blockIdx.z;
    const unsigned short* xn = xb + (size_t)zi * XB_US_PER_IN + (size_t)n * H * SLOT_U;
    float* Rn = (zi ? R2 : R1) + (size_t)n * C * C * NLAG;
    switch (ug) {
        case 0:  autocorr_body< 0, 20>(xn, Rn, sm, threadIdx.x); break;
        case 1:  autocorr_body<20, 40>(xn, Rn, sm, threadIdx.x); break;
        case 2:  autocorr_body<40, 60>(xn, Rn, sm, threadIdx.x); break;
        default: autocorr_body<60, 81>(xn, Rn, sm, threadIdx.x); break;
    }
}

// ---------------------------------------------------------------------------
// fused solve: CG1 (3 it) + CG2 (7 it) + 6-layer CNN, one block per sample.
// ---------------------------------------------------------------------------
__device__ __forceinline__ float block_sum512(float v, float* red, int tid)
{
#pragma unroll
    for (int off = 32; off; off >>= 1) v += __shfl_down(v, off);
    if ((tid & 63) == 0) red[tid >> 6] = v;
    __syncthreads();
    float s = red[0] + red[1] + red[2] + red[3] + red[4] + red[5] + red[6] + red[7];
    __syncthreads();
    return s;
}

__device__ __forceinline__ float cg_solve(const float (&Rg)[81], float rhs, int iters,
                                          float a, int t, float* pv, float* ap, float* red)
{
    const int jj = t & 15;
    float zreg = 0.f, rreg = 0.f, pmine = 0.f;
    if (t < M) {
        rreg = rhs; pmine = rhs;
        pv[(t / 25) * 28 + (t % 25)] = rhs;
    }
    float rr = block_sum512((t < M) ? rreg * rreg : 0.f, red, t);

    for (int it = 0; it < iters; ++it) {
        if (t < 256) {
            float pld[25], acc[25];
            const float* pj = &pv[jj * 28];
#pragma unroll
            for (int k = 0; k < 25; ++k) pld[k] = pj[k];
#pragma unroll
            for (int k = 0; k < 25; ++k) acc[k] = 0.f;
#pragma unroll
            for (int u = 0; u < 9; ++u) {
#pragma unroll
                for (int v = 0; v < 9; ++v) {
                    const float Rv = Rg[u * 9 + v];
#pragma unroll
                    for (int c = 0; c < 5; ++c) {
                        if (c < u - 4 || c > u) continue;
                        const int aa = 4 + c - u;
#pragma unroll
                        for (int dd = 0; dd < 5; ++dd) {
                            if (dd < v - 4 || dd > v) continue;
                            const int bb = 4 + dd - v;
                            acc[aa * 5 + bb] += Rv * pld[c * 5 + dd];
                        }
                    }
                }
            }
#pragma unroll
            for (int k = 0; k < 25; ++k) {
                float s2 = acc[k];
                s2 += __shfl_down(s2, 8, 16);
                s2 += __shfl_down(s2, 4, 16);
                s2 += __shfl_down(s2, 2, 16);
                s2 += __shfl_down(s2, 1, 16);
                acc[k] = s2;
            }
            if (jj == 0) {
#pragma unroll
                for (int k = 0; k < 25; ++k) ap[(t >> 4) * 25 + k] = acc[k];
            }
        }
        __syncthreads();
        float apv = 0.f;
        if (t < M) apv = ap[t] + a * pmine;
        float pAp = block_sum512((t < M) ? pmine * apv : 0.f, red, t);
        float al  = (pAp > 1e-30f) ? rr / pAp : 0.f;
        if (t < M) { zreg += al * pmine; rreg -= al * apv; }
        float rrn = block_sum512(rreg * rreg, red, t);
        float be  = (rr > 1e-30f) ? rrn / rr : 0.f;
        rr = rrn;
        if (t < M) {
            pmine = rreg + be * pmine;
            pv[(t / 25) * 28 + (t % 25)] = pmine;
        }
        __syncthreads();
    }
    return zreg;
}

__global__ __launch_bounds__(512, 2)
void solve_kernel(const float* __restrict__ R1, const float* __restrict__ R2,
                  const float* __restrict__ P1, const float* __restrict__ P2,
                  const float* __restrict__ d0, const float* __restrict__ alpha,
                  const float* __restrict__ beta, const float* __restrict__ reg,
                  const float* __restrict__ w1, const float* __restrict__ b1,
                  const float* __restrict__ w2, const float* __restrict__ b2,
                  const float* __restrict__ w3, const float* __restrict__ b3,
                  const float* __restrict__ w4, const float* __restrict__ b4,
                  const float* __restrict__ w5, const float* __restrict__ b5,
                  const float* __restrict__ w6, const float* __restrict__ b6,
                  float* __restrict__ out)
{
    __shared__ float pv[16 * 28];
    __shared__ float ap[M];
    __shared__ float red[8];
    __shared__ float h0p[25 * 20];
    __shared__ float bufA[25 * 20], bufB[25 * 20];
    __shared__ float wl[16 * 9 * 20];
    __shared__ float bl[16];

    const int n = blockIdx.x, t = threadIdx.x;
    const float a = alpha[n] * (float)(H * W) * reg[0] / (float)(DS * DS * C);
    const int i = (t >> 4) & 15, jj = t & 15;

    float Rg[81];
    if (t < 256) {
        const float* Rp = R1 + (((size_t)n * C + i) * C + jj) * NLAG;
#pragma unroll
        for (int l = 0; l < 81; ++l) Rg[l] = Rp[l];
    }
    float rhs1 = 0.f;
    if (t < M) rhs1 = P1[(size_t)n * M + t] + a * d0[(size_t)n * M + t];
    __syncthreads();
    float z1 = cg_solve(Rg, rhs1, 3, a, t, pv, ap, red);

    if (t < 256) {
        const float* Rp = R2 + (((size_t)n * C + i) * C + jj) * NLAG;
#pragma unroll
        for (int l = 0; l < 81; ++l) Rg[l] = Rp[l];
    }
    float rhs2 = 0.f;
    if (t < M) rhs2 = P2[(size_t)n * M + t] + a * z1;
    __syncthreads();
    float z2 = cg_solve(Rg, rhs2, 7, a, t, pv, ap, red);

    // ---- CNN. Activations [pix][ch] pitch 20; weights [o*9+kk][ci] pitch 20.
    if (t < M) h0p[(t % 25) * 20 + t / 25] = z2;
    if (t < 25) h0p[t * 20 + 16] = rsqrtf(beta[n]);
    __syncthreads();

    const float* wsl[6] = {w1, w2, w3, w4, w5, w6};
    const float* bsl[6] = {b1, b2, b3, b4, b5, b6};

    for (int l = 0; l < 6; ++l) {
        const int cin = (l == 0) ? 17 : 16;
        for (int f = t; f < 16 * cin * 9; f += 512) {
            const int o = f / (cin * 9);
            const int rm = f - o * cin * 9;
            const int ci = rm / 9, kk = rm - ci * 9;
            wl[(o * 9 + kk) * 20 + ci] = wsl[l][f];
        }
        if (t < 16) bl[t] = bsl[l][t];
        __syncthreads();

        const float* act = (l == 0) ? h0p : ((l & 1) ? bufA : bufB);
        float s = 0.f;
        if (t < 400) {
            const int o = t / 25, pix = t % 25, yy = pix / 5, xx = pix % 5;
            s = bl[o];
#pragma unroll
            for (int ky = 0; ky < 3; ++ky) {
                const int iy = yy + ky - 1;
                if ((unsigned)iy >= 5u) continue;
#pragma unroll
                for (int kx = 0; kx < 3; ++kx) {
                    const int ix = xx + kx - 1;
                    if ((unsigned)ix >= 5u) continue;
                    const float* ip = act + (iy * 5 + ix) * 20;
                    const float* wp = wl + (o * 9 + ky * 3 + kx) * 20;
                    const float4 a0 = *(const float4*)(ip);
                    const float4 a1 = *(const float4*)(ip + 4);
                    const float4 a2 = *(const float4*)(ip + 8);
                    const float4 a3 = *(const float4*)(ip + 12);
                    const float4 q0 = *(const float4*)(wp);
                    const float4 q1 = *(const float4*)(wp + 4);
                    const float4 q2 = *(const float4*)(wp + 8);
                    const float4 q3 = *(const float4*)(wp + 12);
                    s += a0.x * q0.x + a0.y * q0.y + a0.z * q0.z + a0.w * q0.w
                       + a1.x * q1.x + a1.y * q1.y + a1.z * q1.z + a1.w * q1.w
                       + a2.x * q2.x + a2.y * q2.y + a2.z * q2.z + a2.w * q2.w
                       + a3.x * q3.x + a3.y * q3.y + a3.z * q3.z + a3.w * q3.w;
                    if (l == 0) s += ip[16] * wp[16];
                }
            }
            if (l < 5) s = fmaxf(s, 0.f);
            else       s += h0p[(t % 25) * 20 + t / 25];
        }
        __syncthreads();
        if (t < 400) {
            if (l == 5) out[(size_t)n * M + t] = s;
            else {
                float* dstb = (l & 1) ? bufB : bufA;
                dstb[(t % 25) * 20 + t / 25] = s;
            }
        }
        __syncthreads();
    }
}

// ---------------------------------------------------------------------------
extern "C" void kernel_launch(void* const* d_in, const int* in_sizes, int n_in,
                              void* d_out, int out_size, void* d_ws, size_t ws_size,
                              hipStream_t stream)
{
    (void)in_sizes; (void)n_in; (void)out_size; (void)ws_size;
    const float* x1    = (const float*)d_in[0];
    const float* x2    = (const float*)d_in[1];
    const float* d0    = (const float*)d_in[2];
    const float* y1    = (const float*)d_in[3];
    const float* y2    = (const float*)d_in[4];
    const float* alpha = (const float*)d_in[5];
    const float* beta  = (const float*)d_in[6];
    const float* reg   = (const float*)d_in[7];
    const float* w1 = (const float*)d_in[8];  const float* b1 = (const float*)d_in[9];
    const float* w2 = (const float*)d_in[10]; const float* b2 = (const float*)d_in[11];
    const float* w3 = (const float*)d_in[12]; const float* b3 = (const float*)d_in[13];
    const float* w4 = (const float*)d_in[14]; const float* b4 = (const float*)d_in[15];
    const float* w5 = (const float*)d_in[16]; const float* b5 = (const float*)d_in[17];
    const float* w6 = (const float*)d_in[18]; const float* b6 = (const float*)d_in[19];
    float* out = (float*)d_out;

    char* wsb = (char*)d_ws;
    unsigned short* xb = (unsigned short*)wsb;                 // 2*10485760 us = 41.9 MB
    float* R1 = (float*)(wsb + 2 * XB_US_PER_IN * 2);
    const size_t RSZ = (size_t)NS * C * C * NLAG;              // 663552 floats
    float* R2 = R1 + RSZ;
    float* P1 = R2 + RSZ;
    float* P2 = P1 + (size_t)NS * M;

    prep_kernel<<<2048, 256, 0, stream>>>(x1, x2, y1, y2, xb, P1, P2);
    autocorr_mfma<<<dim3(NS, 2, 4), 512, 0, stream>>>(xb, R1, R2);
    solve_kernel<<<NS, 512, 0, stream>>>(R1, R2, P1, P2, d0, alpha, beta, reg,
                                         w1, b1, w2, b2, w3, b3, w4, b4,
                                         w5, b5, w6, b6, out);
}

// Round 7
// 322.202 us; speedup vs baseline: 3.0919x; 1.1442x over previous
//
#include <hip/hip_runtime.h>
#include <hip/hip_bf16.h>

constexpr int NS   = 32;
constexpr int C    = 16;
constexpr int H    = 128;
constexpr int W    = 128;
constexpr int DS   = 5;
constexpr int M    = C * DS * DS;   // 400
constexpr int NLAG = 81;

typedef short short8 __attribute__((ext_vector_type(8)));
typedef float f32x4 __attribute__((ext_vector_type(4)));

// bf16 staging layout: xb[zi][n][row][ch][160] ushort:
//   [8 zero][128 data][8 zero][16 zero pad]  -> row-chunk = 16ch*160*2 = 5120 B
constexpr int CH_U    = 160;
constexpr int SLOT_U  = 16 * CH_U;            // 2560 us = 5120 B per row-slot
constexpr int SLOT_B  = SLOT_U * 2;
constexpr int RING_B  = 16 * SLOT_B;          // 81920 B
constexpr size_t XB_US_PER_IN = (size_t)NS * H * 16 * CH_U;   // 10,485,760

__device__ __forceinline__ unsigned int pk_bf16(float a, float b) {
    union { __hip_bfloat162 h; unsigned int u; } cv;
    cv.h = __float22bfloat162_rn(make_float2(a, b));
    return cv.u;
}

__device__ __forceinline__ void gl_lds16(const void* g, void* l) {
    __builtin_amdgcn_global_load_lds(
        (const __attribute__((address_space(1))) unsigned int*)g,
        (__attribute__((address_space(3))) unsigned int*)l, 16, 0, 0);
}

// ---------------------------------------------------------------------------
// prep kernel: blocks 0..1023 convert x->xb (bf16 halo layout);
// blocks 1024..2047 compute crosscorr P.
// ---------------------------------------------------------------------------
__global__ __launch_bounds__(256, 1)
void prep_kernel(const float* __restrict__ x1, const float* __restrict__ x2,
                 const float* __restrict__ y1, const float* __restrict__ y2,
                 unsigned short* __restrict__ xb,
                 float* __restrict__ P1, float* __restrict__ P2)
{
    const int b = blockIdx.x, tid = threadIdx.x;
    if (b < 1024) {
        const int n = b & 31, zi = (b >> 5) & 1, rg = b >> 6;
        const float* xn = (zi ? x2 : x1) + (size_t)n * C * H * W;
        uint4* dst = (uint4*)(xb + (size_t)zi * XB_US_PER_IN +
                              ((size_t)n * H) * SLOT_U);
        for (int f = tid; f < 8 * 16 * 20; f += 256) {
            const int rc = f / 20, g = f - rc * 20;
            const int row = rg * 8 + (rc >> 4), ch = rc & 15;
            uint4 o = make_uint4(0u, 0u, 0u, 0u);
            if (g >= 1 && g <= 16) {
                const float4* s4 = (const float4*)(xn + ((size_t)ch * H + row) * W + (g - 1) * 8);
                float4 va = s4[0], vb = s4[1];
                o.x = pk_bf16(va.x, va.y); o.y = pk_bf16(va.z, va.w);
                o.z = pk_bf16(vb.x, vb.y); o.w = pk_bf16(vb.z, vb.w);
            }
            dst[((size_t)row * 16 + ch) * 20 + g] = o;
        }
        return;
    }
    const int b2 = b - 1024;
    const int n = b2 & 31, j = (b2 >> 5) & 15, zi = b2 >> 9;
    const float* x = zi ? x2 : x1;
    const float* y = zi ? y2 : y1;
    float* P       = zi ? P2 : P1;

    float acc[25];
#pragma unroll
    for (int l = 0; l < 25; ++l) acc[l] = 0.f;
    const float* yn = y + (size_t)n * H * W;
    const float* xc = x + ((size_t)n * C + j) * H * W;

    for (int g = tid; g < 32 * H; g += 256) {
        const int h = g >> 5, wg = g & 31;
        const float4 y4 = *(const float4*)(yn + h * W + wg * 4);
#pragma unroll
        for (int u = 0; u < 5; ++u) {
            const int hr = h + u - 2;
            if ((unsigned)hr >= (unsigned)H) continue;
            const float* xr = xc + hr * W + wg * 4;
            float w12[12];
            float4 t4 = (wg > 0) ? *(const float4*)(xr - 4) : make_float4(0, 0, 0, 0);
            w12[0] = t4.x; w12[1] = t4.y; w12[2] = t4.z; w12[3] = t4.w;
            t4 = *(const float4*)(xr);
            w12[4] = t4.x; w12[5] = t4.y; w12[6] = t4.z; w12[7] = t4.w;
            t4 = (wg < 31) ? *(const float4*)(xr + 4) : make_float4(0, 0, 0, 0);
            w12[8] = t4.x; w12[9] = t4.y; w12[10] = t4.z; w12[11] = t4.w;
#pragma unroll
            for (int v = 0; v < 5; ++v)
                acc[u * 5 + v] += y4.x * w12[2 + v] + y4.y * w12[3 + v] +
                                  y4.z * w12[4 + v] + y4.w * w12[5 + v];
        }
    }
    __shared__ float red[4][25];
    const int lane = tid & 63, wv = tid >> 6;
#pragma unroll
    for (int l = 0; l < 25; ++l) {
        float v = acc[l];
#pragma unroll
        for (int off = 32; off; off >>= 1) v += __shfl_down(v, off);
        if (lane == 0) red[wv][l] = v;
    }
    __syncthreads();
    if (tid < 25)
        P[((size_t)n * C + j) * 25 + tid] = red[0][tid] + red[1][tid] + red[2][tid] + red[3][tid];
}

// ---------------------------------------------------------------------------
// MFMA autocorr: grid (n, zi, ug:4), 512 threads (8 waves).
// ---------------------------------------------------------------------------
template<int P0, int P1>
__device__ __forceinline__ void autocorr_body(const unsigned short* __restrict__ xn,
                                              float* __restrict__ Rn,
                                              char* sm, int tid)
{
    constexpr int U0 = P0 / 9;
    constexpr int U1 = (P1 - 1) / 9;
    constexpr int NB = U1 - U0 + 1;
    constexpr int NP = P1 - P0;

    unsigned short* ring = (unsigned short*)sm;
    const int lane = tid & 63;
    const int wid  = tid >> 6;
    const int q    = lane >> 4;
    const int mi   = lane & 15;
    const int rh   = wid & 3;
    const int chh  = wid >> 2;

    f32x4 acc[NP];
#pragma unroll
    for (int l = 0; l < NP; ++l) acc[l] = (f32x4){0.f, 0.f, 0.f, 0.f};

    const char* gb = (const char*)xn;

    for (int f = tid; f < 4 * 320; f += 512)
        ((uint4*)sm)[(12 + f / 320) * 320 + (f % 320)] = make_uint4(0, 0, 0, 0);
    for (int f = wid; f < 40; f += 8) {
        const int row = f / 5, e = f - row * 5;
        gl_lds16(gb + (size_t)row * SLOT_B + e * 1024 + lane * 16,
                 sm + row * SLOT_B + e * 1024);
    }
    __syncthreads();

    for (int s = 0; s < H; s += 4) {
        if (s < H - 8) {
            for (int f = wid; f < 20; f += 8) {
                const int row = s + 8 + f / 5, e = f - (f / 5) * 5;
                gl_lds16(gb + (size_t)row * SLOT_B + e * 1024 + lane * 16,
                         sm + (row & 15) * SLOT_B + e * 1024);
            }
        } else {
            for (int f = tid; f < 4 * 320; f += 512)
                ((uint4*)sm)[(((s + 8 + f / 320) & 15)) * 320 + (f % 320)] = make_uint4(0, 0, 0, 0);
        }

        const int r = s + rh;
        const unsigned short* rowA = ring + (r & 15) * SLOT_U + mi * CH_U;
#pragma unroll
        for (int cc = 0; cc < 2; ++cc) {
            const int w0 = (chh * 2 + cc) * 32;
            const uint4* pa = (const uint4*)(rowA + w0 + 8 * q);
            uint4 A0 = pa[0], A1 = pa[1], A2 = pa[2];
            unsigned int d[12] = {A0.x, A0.y, A0.z, A0.w, A1.x, A1.y, A1.z, A1.w,
                                  A2.x, A2.y, A2.z, A2.w};
            short8 bf[NB];
#pragma unroll
            for (int u = U0; u <= U1; ++u)
                bf[u - U0] = *(const short8*)(ring + ((r + u - 4 + 16) & 15) * SLOT_U +
                                              mi * CH_U + 8 + w0 + 8 * q);
#pragma unroll
            for (int v = 0; v < 9; ++v) {
                const int off = 12 - v;
                const int q4  = off >> 1;
                union { unsigned int u4[4]; short8 s8; } af;
                if (off & 1) {
#pragma unroll
                    for (int k2 = 0; k2 < 4; ++k2)
                        af.u4[k2] = (d[q4 + k2] >> 16) | (d[q4 + k2 + 1] << 16);
                } else {
#pragma unroll
                    for (int k2 = 0; k2 < 4; ++k2) af.u4[k2] = d[q4 + k2];
                }
#pragma unroll
                for (int u = U0; u <= U1; ++u) {
                    if (u * 9 + v >= P0 && u * 9 + v < P1)
                        acc[u * 9 + v - P0] = __builtin_amdgcn_mfma_f32_16x16x32_bf16(
                            af.s8, bf[u - U0], acc[u * 9 + v - P0], 0, 0, 0);
                }
            }
        }
        __syncthreads();
    }

    float* sred = (float*)sm;
#pragma unroll
    for (int cb = 0; cb < NP; cb += 9) {
        const int nc = (NP - cb < 9) ? (NP - cb) : 9;
        __syncthreads();
#pragma unroll
        for (int pp = 0; pp < 9; ++pp) {
            if (pp < nc) {
#pragma unroll
                for (int rg = 0; rg < 4; ++rg)
                    sred[(pp * 8 + wid) * 256 + (q * 4 + rg) * 16 + mi] = acc[cb + pp][rg];
            }
        }
        __syncthreads();
        if (tid < 256) {
#pragma unroll
            for (int pp = 0; pp < 9; ++pp) {
                if (pp < nc) {
                    float ssum = 0.f;
#pragma unroll
                    for (int w8 = 0; w8 < 8; ++w8)
                        ssum += sred[(pp * 8 + w8) * 256 + tid];
                    Rn[(size_t)tid * NLAG + P0 + cb + pp] = ssum;
                }
            }
        }
    }
}

__global__ __launch_bounds__(512, 2)
void autocorr_mfma(const unsigned short* __restrict__ xb,
                   float* __restrict__ R1, float* __restrict__ R2)
{
    __shared__ __align__(16) char sm[RING_B];
    const int n = blockIdx.x, zi = blockIdx.y, ug = blockIdx.z;
    const unsigned short* xn = xb + (size_t)zi * XB_US_PER_IN + (size_t)n * H * SLOT_U;
    float* Rn = (zi ? R2 : R1) + (size_t)n * C * C * NLAG;
    switch (ug) {
        case 0:  autocorr_body< 0, 20>(xn, Rn, sm, threadIdx.x); break;
        case 1:  autocorr_body<20, 40>(xn, Rn, sm, threadIdx.x); break;
        case 2:  autocorr_body<40, 60>(xn, Rn, sm, threadIdx.x); break;
        default: autocorr_body<60, 81>(xn, Rn, sm, threadIdx.x); break;
    }
}

// ---------------------------------------------------------------------------
// fused solve: CG1 (3 it) + CG2 (7 it) + 6-layer CNN, one block per sample.
// R block lives in LDS (flat layout Rl[t*81+l]; 81%32=17 coprime -> 64 distinct
// banks on reads); staged via async global_load_lds (linear copy). No big
// register arrays -> no spill / no per-iter global re-reads (R6 failure mode).
// ---------------------------------------------------------------------------
__device__ __forceinline__ float block_sum512(float v, float* red, int tid)
{
#pragma unroll
    for (int off = 32; off; off >>= 1) v += __shfl_down(v, off);
    if ((tid & 63) == 0) red[tid >> 6] = v;
    __syncthreads();
    float s = red[0] + red[1] + red[2] + red[3] + red[4] + red[5] + red[6] + red[7];
    __syncthreads();
    return s;
}

__device__ __forceinline__ float cg_solve(const float* __restrict__ Rrow, float rhs,
                                          int iters, float a, int t,
                                          float* pv, float* ap, float* red)
{
    const int jj = t & 15;
    float zreg = 0.f, rreg = 0.f, pmine = 0.f;
    if (t < M) {
        rreg = rhs; pmine = rhs;
        pv[(t / 25) * 28 + (t % 25)] = rhs;
    }
    float rr = block_sum512((t < M) ? rreg * rreg : 0.f, red, t);

    for (int it = 0; it < iters; ++it) {
        if (t < 256) {
            float pld[25], acc[25];
            const float* pj = &pv[jj * 28];
#pragma unroll
            for (int k = 0; k < 25; ++k) pld[k] = pj[k];
#pragma unroll
            for (int k = 0; k < 25; ++k) acc[k] = 0.f;
#pragma unroll
            for (int u = 0; u < 9; ++u) {
#pragma unroll
                for (int v = 0; v < 9; ++v) {
                    const float Rv = Rrow[u * 9 + v];      // LDS scalar read
#pragma unroll
                    for (int c = 0; c < 5; ++c) {
                        if (c < u - 4 || c > u) continue;
                        const int aa = 4 + c - u;
#pragma unroll
                        for (int dd = 0; dd < 5; ++dd) {
                            if (dd < v - 4 || dd > v) continue;
                            const int bb = 4 + dd - v;
                            acc[aa * 5 + bb] += Rv * pld[c * 5 + dd];
                        }
                    }
                }
            }
#pragma unroll
            for (int k = 0; k < 25; ++k) {
                float s2 = acc[k];
                s2 += __shfl_down(s2, 8, 16);
                s2 += __shfl_down(s2, 4, 16);
                s2 += __shfl_down(s2, 2, 16);
                s2 += __shfl_down(s2, 1, 16);
                acc[k] = s2;
            }
            if (jj == 0) {
#pragma unroll
                for (int k = 0; k < 25; ++k) ap[(t >> 4) * 25 + k] = acc[k];
            }
        }
        __syncthreads();
        float apv = 0.f;
        if (t < M) apv = ap[t] + a * pmine;
        float pAp = block_sum512((t < M) ? pmine * apv : 0.f, red, t);
        float al  = (pAp > 1e-30f) ? rr / pAp : 0.f;
        if (t < M) { zreg += al * pmine; rreg -= al * apv; }
        float rrn = block_sum512(rreg * rreg, red, t);
        float be  = (rr > 1e-30f) ? rrn / rr : 0.f;
        rr = rrn;
        if (t < M) {
            pmine = rreg + be * pmine;
            pv[(t / 25) * 28 + (t % 25)] = pmine;
        }
        __syncthreads();
    }
    return zreg;
}

__global__ __launch_bounds__(512, 1)
void solve_kernel(const float* __restrict__ R1, const float* __restrict__ R2,
                  const float* __restrict__ P1, const float* __restrict__ P2,
                  const float* __restrict__ d0, const float* __restrict__ alpha,
                  const float* __restrict__ beta, const float* __restrict__ reg,
                  const float* __restrict__ w1, const float* __restrict__ b1,
                  const float* __restrict__ w2, const float* __restrict__ b2,
                  const float* __restrict__ w3, const float* __restrict__ b3,
                  const float* __restrict__ w4, const float* __restrict__ b4,
                  const float* __restrict__ w5, const float* __restrict__ b5,
                  const float* __restrict__ w6, const float* __restrict__ b6,
                  float* __restrict__ out)
{
    __shared__ __align__(16) float Rl[256 * NLAG];   // 82944 B
    __shared__ float pv[16 * 28];
    __shared__ float ap[M];
    __shared__ float red[8];
    __shared__ float h0p[25 * 20];
    __shared__ float bufA[25 * 20], bufB[25 * 20];
    __shared__ float wl[16 * 9 * 20];
    __shared__ float bl[16];

    const int n = blockIdx.x, t = threadIdx.x;
    const float a = alpha[n] * (float)(H * W) * reg[0] / (float)(DS * DS * C);

    // stage R1 -> LDS (flat linear, async dma)
    {
        const char* g = (const char*)(R1 + (size_t)n * 256 * NLAG);
        char* l = (char*)Rl;
        for (int f = t; f < 256 * NLAG / 4; f += 512)
            gl_lds16(g + (size_t)f * 16, l + (size_t)f * 16);
    }
    float rhs1 = 0.f;
    if (t < M) rhs1 = P1[(size_t)n * M + t] + a * d0[(size_t)n * M + t];
    __syncthreads();   // drains the DMA
    float z1 = cg_solve(&Rl[(t & 255) * NLAG], rhs1, 3, a, t, pv, ap, red);

    __syncthreads();   // all reads of Rl done
    {
        const char* g = (const char*)(R2 + (size_t)n * 256 * NLAG);
        char* l = (char*)Rl;
        for (int f = t; f < 256 * NLAG / 4; f += 512)
            gl_lds16(g + (size_t)f * 16, l + (size_t)f * 16);
    }
    float rhs2 = 0.f;
    if (t < M) rhs2 = P2[(size_t)n * M + t] + a * z1;
    __syncthreads();
    float z2 = cg_solve(&Rl[(t & 255) * NLAG], rhs2, 7, a, t, pv, ap, red);

    // ---- CNN. Activations [pix][ch] pitch 20; weights [o*9+kk][ci] pitch 20.
    if (t < M) h0p[(t % 25) * 20 + t / 25] = z2;
    if (t < 25) h0p[t * 20 + 16] = rsqrtf(beta[n]);
    __syncthreads();

    const float* wsl[6] = {w1, w2, w3, w4, w5, w6};
    const float* bsl[6] = {b1, b2, b3, b4, b5, b6};

    for (int l = 0; l < 6; ++l) {
        const int cin = (l == 0) ? 17 : 16;
        for (int f = t; f < 16 * cin * 9; f += 512) {
            const int o = f / (cin * 9);
            const int rm = f - o * cin * 9;
            const int ci = rm / 9, kk = rm - ci * 9;
            wl[(o * 9 + kk) * 20 + ci] = wsl[l][f];
        }
        if (t < 16) bl[t] = bsl[l][t];
        __syncthreads();

        const float* act = (l == 0) ? h0p : ((l & 1) ? bufA : bufB);
        float s = 0.f;
        if (t < 400) {
            const int o = t / 25, pix = t % 25, yy = pix / 5, xx = pix % 5;
            s = bl[o];
#pragma unroll
            for (int ky = 0; ky < 3; ++ky) {
                const int iy = yy + ky - 1;
                if ((unsigned)iy >= 5u) continue;
#pragma unroll
                for (int kx = 0; kx < 3; ++kx) {
                    const int ix = xx + kx - 1;
                    if ((unsigned)ix >= 5u) continue;
                    const float* ip = act + (iy * 5 + ix) * 20;
                    const float* wp = wl + (o * 9 + ky * 3 + kx) * 20;
                    const float4 a0 = *(const float4*)(ip);
                    const float4 a1 = *(const float4*)(ip + 4);
                    const float4 a2 = *(const float4*)(ip + 8);
                    const float4 a3 = *(const float4*)(ip + 12);
                    const float4 q0 = *(const float4*)(wp);
                    const float4 q1 = *(const float4*)(wp + 4);
                    const float4 q2 = *(const float4*)(wp + 8);
                    const float4 q3 = *(const float4*)(wp + 12);
                    s += a0.x * q0.x + a0.y * q0.y + a0.z * q0.z + a0.w * q0.w
                       + a1.x * q1.x + a1.y * q1.y + a1.z * q1.z + a1.w * q1.w
                       + a2.x * q2.x + a2.y * q2.y + a2.z * q2.z + a2.w * q2.w
                       + a3.x * q3.x + a3.y * q3.y + a3.z * q3.z + a3.w * q3.w;
                    if (l == 0) s += ip[16] * wp[16];
                }
            }
            if (l < 5) s = fmaxf(s, 0.f);
            else       s += h0p[(t % 25) * 20 + t / 25];
        }
        __syncthreads();
        if (t < 400) {
            if (l == 5) out[(size_t)n * M + t] = s;
            else {
                float* dstb = (l & 1) ? bufB : bufA;
                dstb[(t % 25) * 20 + t / 25] = s;
            }
        }
        __syncthreads();
    }
}

// ---------------------------------------------------------------------------
extern "C" void kernel_launch(void* const* d_in, const int* in_sizes, int n_in,
                              void* d_out, int out_size, void* d_ws, size_t ws_size,
                              hipStream_t stream)
{
    (void)in_sizes; (void)n_in; (void)out_size; (void)ws_size;
    const float* x1    = (const float*)d_in[0];
    const float* x2    = (const float*)d_in[1];
    const float* d0    = (const float*)d_in[2];
    const float* y1    = (const float*)d_in[3];
    const float* y2    = (const float*)d_in[4];
    const float* alpha = (const float*)d_in[5];
    const float* beta  = (const float*)d_in[6];
    const float* reg   = (const float*)d_in[7];
    const float* w1 = (const float*)d_in[8];  const float* b1 = (const float*)d_in[9];
    const float* w2 = (const float*)d_in[10]; const float* b2 = (const float*)d_in[11];
    const float* w3 = (const float*)d_in[12]; const float* b3 = (const float*)d_in[13];
    const float* w4 = (const float*)d_in[14]; const float* b4 = (const float*)d_in[15];
    const float* w5 = (const float*)d_in[16]; const float* b5 = (const float*)d_in[17];
    const float* w6 = (const float*)d_in[18]; const float* b6 = (const float*)d_in[19];
    float* out = (float*)d_out;

    char* wsb = (char*)d_ws;
    unsigned short* xb = (unsigned short*)wsb;                 // 41.9 MB
    float* R1 = (float*)(wsb + 2 * XB_US_PER_IN * 2);
    const size_t RSZ = (size_t)NS * C * C * NLAG;              // 663552 floats
    float* R2 = R1 + RSZ;
    float* P1 = R2 + RSZ;
    float* P2 = P1 + (size_t)NS * M;

    prep_kernel<<<2048, 256, 0, stream>>>(x1, x2, y1, y2, xb, P1, P2);
    autocorr_mfma<<<dim3(NS, 2, 4), 512, 0, stream>>>(xb, R1, R2);
    solve_kernel<<<NS, 512, 0, stream>>>(R1, R2, P1, P2, d0, alpha, beta, reg,
                                         w1, b1, w2, b2, w3, b3, w4, b4,
                                         w5, b5, w6, b6, out);
}